// Round 4
// baseline (1231.653 us; speedup 1.0000x reference)
//
#include <hip/hip_runtime.h>
#include <math.h>

#define NVV 25000
#define NCC 12500
#define NEE 250000
#define KP 160   // padded K for all bf16 GEMM inputs (covers K=128,136,144)

typedef short bf16x8 __attribute__((ext_vector_type(8)));
typedef float f32x4 __attribute__((ext_vector_type(4)));

// ---------- helpers ----------
__device__ __forceinline__ unsigned short f2bf(float f) {  // RNE fp32->bf16
  unsigned u = __float_as_uint(f);
  u += 0x7fffu + ((u >> 16) & 1u);
  return (unsigned short)(u >> 16);
}

// ---------- bf16 MFMA GEMM, LDS-free: out[N,128] = X[N,160]bf16 @ WT^T ----------
// A fragments loaded straight global->VGPR (each wave owns its 32 rows; rows read
// exactly once, 64B-segment coalesced). B = WT[128,160] is 40KB -> L2-resident;
// fragments loaded straight from L2. No LDS, no barriers -> pure load/MFMA pipeline.
__global__ __launch_bounds__(256, 2) void gemm_mfma(
    const unsigned short* __restrict__ X, const unsigned short* __restrict__ WT,
    const float* __restrict__ bias, float* __restrict__ outf,
    unsigned short* __restrict__ outb, int outb_stride, int pad_flag,
    const float* __restrict__ gA, const float* __restrict__ gB,
    const int* __restrict__ giA, const int* __restrict__ giB,
    int N, int relu_flag) {
  int tid = threadIdx.x;
  int lane = tid & 63, wave = tid >> 6;
  int fr = lane & 15, fq = lane >> 4;
  int row0 = blockIdx.x * 128 + wave * 32;   // this wave: rows row0..row0+31

  f32x4 acc[2][8];
  #pragma unroll
  for (int mi = 0; mi < 2; ++mi)
    #pragma unroll
    for (int ni = 0; ni < 8; ++ni) {
      acc[mi][ni][0] = 0.f; acc[mi][ni][1] = 0.f;
      acc[mi][ni][2] = 0.f; acc[mi][ni][3] = 0.f;
    }

  // A row pointers (clamped; only the last block clamps, within its own rows)
  const unsigned short* aptr[2];
  #pragma unroll
  for (int mi = 0; mi < 2; ++mi) {
    int r = row0 + mi * 16 + fr;
    if (r >= N) r = N - 1;
    aptr[mi] = X + (size_t)r * KP + fq * 8;
  }
  // B col base: col = ni*16 + fr
  const unsigned short* bptr = WT + (size_t)fr * KP + fq * 8;

  for (int k0 = 0; k0 < KP; k0 += 32) {
    bf16x8 a[2], b[8];
    #pragma unroll
    for (int mi = 0; mi < 2; ++mi)
      a[mi] = *(const bf16x8*)(aptr[mi] + k0);
    #pragma unroll
    for (int ni = 0; ni < 8; ++ni)
      b[ni] = *(const bf16x8*)(bptr + (size_t)ni * 16 * KP + k0);
    #pragma unroll
    for (int mi = 0; mi < 2; ++mi)
      #pragma unroll
      for (int ni = 0; ni < 8; ++ni)
        acc[mi][ni] = __builtin_amdgcn_mfma_f32_16x16x32_bf16(a[mi], b[ni], acc[mi][ni], 0, 0, 0);
  }

  // epilogue: C/D layout col=lane&15, row=(lane>>4)*4+reg
  #pragma unroll
  for (int mi = 0; mi < 2; ++mi) {
    #pragma unroll
    for (int ni = 0; ni < 8; ++ni) {
      int gcol = ni * 16 + fr;
      float bvv = bias ? bias[gcol] : 0.0f;
      #pragma unroll
      for (int r = 0; r < 4; ++r) {
        int grow = row0 + mi * 16 + fq * 4 + r;
        if (grow < N) {
          float o = acc[mi][ni][r] + bvv;
          if (gA) o += gA[(size_t)giA[grow] * 128 + gcol] + gB[(size_t)giB[grow] * 128 + gcol];
          if (relu_flag) o = fmaxf(o, 0.f);
          if (outf) outf[(size_t)grow * 128 + gcol] = o;
          if (outb) outb[(size_t)grow * outb_stride + gcol] = f2bf(o);
        }
      }
    }
    if (outb && pad_flag) {  // zero pad cols 128..159: 16 lanes x ushort2 = one 64B segment/row
      #pragma unroll
      for (int r = 0; r < 4; ++r) {
        int grow = row0 + mi * 16 + fq * 4 + r;
        if (grow < N) {
          ushort2 z; z.x = 0; z.y = 0;
          *(ushort2*)&outb[(size_t)grow * outb_stride + 128 + fr * 2] = z;
        }
      }
    }
  }
}

// ---------- build bf16 combined features ----------
__global__ void build_node_bf(const float* __restrict__ learned, const float* __restrict__ lp,
                              unsigned short* __restrict__ out, int N) {
  int idx = blockIdx.x * blockDim.x + threadIdx.x;
  if (idx >= N * 40) return;
  int row = idx / 40, c4 = idx - row * 40;
  int c = c4 * 4;
  ushort4 o;
  if (c4 < 32) {
    const float* p = learned + (size_t)row * 128 + c;
    o.x = f2bf(p[0]); o.y = f2bf(p[1]); o.z = f2bf(p[2]); o.w = f2bf(p[3]);
  } else if (c4 < 36) {
    const float* p = lp + (size_t)row * 16 + (c - 128);
    o.x = f2bf(p[0]); o.y = f2bf(p[1]); o.z = f2bf(p[2]); o.w = f2bf(p[3]);
  } else { o.x = o.y = o.z = o.w = 0; }
  *(ushort4*)&out[(size_t)row * KP + c] = o;
}

__global__ void build_edge_bf(const float* __restrict__ el, const float* __restrict__ lo,
                              const float* __restrict__ hi, const float* __restrict__ dm,
                              const float* __restrict__ wo, unsigned short* __restrict__ out) {
  int idx = blockIdx.x * blockDim.x + threadIdx.x;
  if (idx >= NEE * 40) return;
  int row = idx / 40, c4 = idx - row * 40;
  int c = c4 * 4;
  ushort4 o;
  if (c4 < 32) {
    const float* p = el + (size_t)row * 128 + c;
    o.x = f2bf(p[0]); o.y = f2bf(p[1]); o.z = f2bf(p[2]); o.w = f2bf(p[3]);
  } else if (c4 == 32) {
    o.x = f2bf(lo[row]); o.y = f2bf(hi[row]); o.z = f2bf(dm[row]);
    o.w = f2bf(wo[(size_t)row * 5 + 0]);
  } else if (c4 == 33) {
    const float* p = wo + (size_t)row * 5;
    o.x = f2bf(p[1]); o.y = f2bf(p[2]); o.z = f2bf(p[3]); o.w = f2bf(p[4]);
  } else { o.x = o.y = o.z = o.w = 0; }
  *(ushort4*)&out[(size_t)row * KP + c] = o;
}

// ---------- weight transpose + convert ----------
struct WJobs {
  const float* W[18];
  unsigned short* O[18];
  int K[18];
};
__global__ void convert_weights(WJobs j) {
  int b = blockIdx.x;
  int job = b / 80;
  int i = (b - job * 80) * 256 + threadIdx.x;
  int col = i / KP;
  int k = i - col * KP;
  int K = j.K[job];
  j.O[job][(size_t)col * KP + k] =
      (k < K) ? f2bf(j.W[job][(size_t)k * 128 + col]) : (unsigned short)0;
}

// ---------- CSR construction ----------
__global__ void zero2(int* __restrict__ a, int na, int* __restrict__ b, int nb) {
  int i = blockIdx.x * blockDim.x + threadIdx.x;
  if (i < na) a[i] = 0;
  if (i < nb) b[i] = 0;
}
__global__ void hist2(const int* __restrict__ dc, int* __restrict__ cc,
                      const int* __restrict__ dv, int* __restrict__ cv, int nE) {
  int e = blockIdx.x * blockDim.x + threadIdx.x;
  if (e >= nE) return;
  atomicAdd(&cc[dc[e]], 1);
  atomicAdd(&cv[dv[e]], 1);
}
// single block 256 threads
__global__ void csr_scan(const int* __restrict__ counts, int* __restrict__ offsets,
                         int* __restrict__ cursor, int n) {
  __shared__ int part[256];
  int tid = threadIdx.x;
  int chunk = (n + 255) / 256;
  int lo = tid * chunk, hi = min(n, lo + chunk);
  int s = 0;
  for (int i = lo; i < hi; ++i) s += counts[i];
  part[tid] = s;
  __syncthreads();
  if (tid == 0) {
    int run = 0;
    for (int i = 0; i < 256; ++i) { int t = part[i]; part[i] = run; run += t; }
    offsets[n] = run;
  }
  __syncthreads();
  int base = part[tid];
  for (int i = lo; i < hi; ++i) { offsets[i] = base; cursor[i] = base; base += counts[i]; }
}
__global__ void csr_scatter(const int* __restrict__ dst, const int* __restrict__ src,
                            int* __restrict__ cursor, int* __restrict__ ce,
                            int* __restrict__ cs, int nE) {
  int e = blockIdx.x * blockDim.x + threadIdx.x;
  if (e >= nE) return;
  int pos = atomicAdd(&cursor[dst[e]], 1);
  ce[pos] = e;
  cs[pos] = src[e];
}

// ---------- fused flash-style segment attention: one wave per dst ----------
__global__ __launch_bounds__(256) void fused_attn(
    const float* __restrict__ qbuf, const float* __restrict__ kbuf,
    const float* __restrict__ vbuf, const unsigned short* __restrict__ ee,
    const int* __restrict__ offsets, const int* __restrict__ ce,
    const int* __restrict__ cs, const float* __restrict__ skip,
    float* __restrict__ outd, unsigned short* __restrict__ comb, int Nd) {
  int d = blockIdx.x * 4 + (threadIdx.x >> 6);
  if (d >= Nd) return;
  int lane = threadIdx.x & 63;
  int c = lane * 2;
  float2 qv = *(const float2*)&qbuf[(size_t)d * 128 + c];
  int beg = offsets[d], end = offsets[d + 1];
  float m = -INFINITY, l = 0.f;
  float ax = 0.f, ay = 0.f;
  for (int i = beg; i < end; ++i) {
    int e = ce[i], s = cs[i];
    unsigned eu = *(const unsigned*)&ee[(size_t)e * 128 + c];
    float e0 = __uint_as_float(eu << 16);
    float e1 = __uint_as_float(eu & 0xffff0000u);
    float2 kv = *(const float2*)&kbuf[(size_t)s * 128 + c];
    float2 vv = *(const float2*)&vbuf[(size_t)s * 128 + c];
    float p = qv.x * (kv.x + e0) + qv.y * (kv.y + e1);
    #pragma unroll
    for (int off = 1; off < 64; off <<= 1) p += __shfl_xor(p, off, 64);
    float alpha = p * 0.08838834764831845f;  // 1/sqrt(128)
    float mn = fmaxf(m, alpha);
    float scale = __expf(m - mn);            // first iter: exp(-inf)=0
    float w = __expf(alpha - mn);
    ax = ax * scale + (vv.x + e0) * w;
    ay = ay * scale + (vv.y + e1) * w;
    l = l * scale + w;
    m = mn;
  }
  int deg = end - beg;
  float inv = (deg > 0) ? 1.0f / (l * (float)deg) : 0.0f;
  float2 sk = *(const float2*)&skip[(size_t)d * 128 + c];
  float o0 = fmaxf(ax * inv + sk.x, 0.f);
  float o1 = fmaxf(ay * inv + sk.y, 0.f);
  *(float2*)&outd[(size_t)d * 128 + c] = make_float2(o0, o1);
  ushort2 ob; ob.x = f2bf(o0); ob.y = f2bf(o1);
  *(ushort2*)&comb[(size_t)d * KP + c] = ob;
}

static inline void gemm(const unsigned short* X, const unsigned short* WT, const float* bias,
                        float* outf, unsigned short* outb, int obstride, int pad,
                        const float* gA, const float* gB, const int* giA, const int* giB,
                        int N, int relu, hipStream_t s) {
  gemm_mfma<<<(N + 127) / 128, 256, 0, s>>>(X, WT, bias, outf, outb, obstride, pad,
                                            gA, gB, giA, giB, N, relu);
}

extern "C" void kernel_launch(void* const* d_in, const int* in_sizes, int n_in,
                              void* d_out, int out_size, void* d_ws, size_t ws_size,
                              hipStream_t stream) {
  const float* var_learned = (const float*)d_in[0];
  const float* var_lp      = (const float*)d_in[1];
  const float* con_learned = (const float*)d_in[2];
  const float* con_lp      = (const float*)d_in[3];
  const float* edge_learned= (const float*)d_in[4];
  const float* lo          = (const float*)d_in[5];
  const float* hi          = (const float*)d_in[6];
  const float* dm          = (const float*)d_in[7];
  const float* wo          = (const float*)d_in[8];
  const float* cu_Wq = (const float*)d_in[9],  *cu_bq = (const float*)d_in[10];
  const float* cu_Wk = (const float*)d_in[11], *cu_bk = (const float*)d_in[12];
  const float* cu_Wv = (const float*)d_in[13], *cu_bv = (const float*)d_in[14];
  const float* cu_We = (const float*)d_in[15];
  const float* cu_Ws = (const float*)d_in[16], *cu_bs = (const float*)d_in[17];
  const float* vu_Wq = (const float*)d_in[18], *vu_bq = (const float*)d_in[19];
  const float* vu_Wk = (const float*)d_in[20], *vu_bk = (const float*)d_in[21];
  const float* vu_Wv = (const float*)d_in[22], *vu_bv = (const float*)d_in[23];
  const float* vu_We = (const float*)d_in[24];
  const float* vu_Ws = (const float*)d_in[25], *vu_bs = (const float*)d_in[26];
  const float* eu_vW1 = (const float*)d_in[27], *eu_vb1 = (const float*)d_in[28];
  const float* eu_vW2 = (const float*)d_in[29], *eu_vb2 = (const float*)d_in[30];
  const float* eu_cW1 = (const float*)d_in[31], *eu_cb1 = (const float*)d_in[32];
  const float* eu_cW2 = (const float*)d_in[33], *eu_cb2 = (const float*)d_in[34];
  const float* eu_eW1 = (const float*)d_in[35], *eu_eb1 = (const float*)d_in[36];
  const float* eu_eW2 = (const float*)d_in[37], *eu_eb2 = (const float*)d_in[38];
  const int* eiv = (const int*)d_in[39];
  const int* eic = (const int*)d_in[40];

  float* out_var  = (float*)d_out;
  float* out_con  = out_var + (size_t)NVV * 128;
  float* out_edge = out_con + (size_t)NCC * 128;

  // ---- workspace arena ----
  char* w = (char*)d_ws;
  auto alloc = [&](size_t bytes) { char* p = w; w += (bytes + 255) & ~(size_t)255; return p; };
  unsigned short* edge_comb_bf = (unsigned short*)alloc((size_t)NEE * KP * 2);  // aliased te_bf
  unsigned short* ee_bf = (unsigned short*)alloc((size_t)NEE * 128 * 2);
  unsigned short* var_comb_bf = (unsigned short*)alloc((size_t)NVV * KP * 2);
  unsigned short* con_comb_bf = (unsigned short*)alloc((size_t)NCC * KP * 2);
  unsigned short* hidV_bf = (unsigned short*)alloc((size_t)NVV * KP * 2);
  unsigned short* vc_bf   = (unsigned short*)alloc((size_t)NVV * KP * 2);
  unsigned short* hidC_bf = (unsigned short*)alloc((size_t)NCC * KP * 2);
  unsigned short* cc_bf   = (unsigned short*)alloc((size_t)NCC * KP * 2);
  float* bufV1 = (float*)alloc((size_t)NVV * 128 * 4);
  float* bufV2 = (float*)alloc((size_t)NVV * 128 * 4);
  float* bufC1 = (float*)alloc((size_t)NCC * 128 * 4);
  float* bufC2 = (float*)alloc((size_t)NCC * 128 * 4);
  unsigned short* WTbase = (unsigned short*)alloc((size_t)18 * 128 * KP * 2);
  int* countsC = (int*)alloc((size_t)NCC * 4);
  int* countsV = (int*)alloc((size_t)NVV * 4);
  int* offC = (int*)alloc((size_t)(NCC + 1) * 4);
  int* curC = (int*)alloc((size_t)NCC * 4);
  int* offV = (int*)alloc((size_t)(NVV + 1) * 4);
  int* curV = (int*)alloc((size_t)NVV * 4);
  int* ceA = (int*)alloc((size_t)NEE * 4);
  int* csA = (int*)alloc((size_t)NEE * 4);
  int* ceB = (int*)alloc((size_t)NEE * 4);
  int* csB = (int*)alloc((size_t)NEE * 4);
  unsigned short* te_bf = edge_comb_bf;  // safe alias: each block reads only its own rows
  (void)ws_size; (void)in_sizes; (void)n_in; (void)out_size;

  unsigned short* WT[18];
  for (int i = 0; i < 18; ++i) WT[i] = WTbase + (size_t)i * 128 * KP;
  WJobs jobs;
  const float* Wsrc[18] = {cu_Wq, cu_Wk, cu_Wv, cu_We, cu_Ws,
                           vu_Wq, vu_Wk, vu_Wv, vu_We, vu_Ws,
                           eu_vW1, eu_vW2, eu_cW1, eu_cW2,
                           eu_eW1, eu_eW1 + 136 * 128, eu_eW1 + 264 * 128, eu_eW2};
  const int Ksrc[18] = {144, 144, 144, 136, 144, 144, 144, 144, 136, 144,
                        144, 128, 144, 128, 136, 128, 128, 128};
  for (int i = 0; i < 18; ++i) { jobs.W[i] = Wsrc[i]; jobs.O[i] = WT[i]; jobs.K[i] = Ksrc[i]; }

  const int T = 256;

  // ---- pre-passes ----
  build_node_bf<<<(NVV * 40 + T - 1) / T, T, 0, stream>>>(var_learned, var_lp, var_comb_bf, NVV);
  build_node_bf<<<(NCC * 40 + T - 1) / T, T, 0, stream>>>(con_learned, con_lp, con_comb_bf, NCC);
  build_edge_bf<<<(NEE * 40 + T - 1) / T, T, 0, stream>>>(edge_learned, lo, hi, dm, wo, edge_comb_bf);
  convert_weights<<<18 * 80, T, 0, stream>>>(jobs);

  // ---- CSR builds ----
  zero2<<<(NVV + T - 1) / T, T, 0, stream>>>(countsC, NCC, countsV, NVV);
  hist2<<<(NEE + T - 1) / T, T, 0, stream>>>(eic, countsC, eiv, countsV, NEE);
  csr_scan<<<1, 256, 0, stream>>>(countsC, offC, curC, NCC);
  csr_scan<<<1, 256, 0, stream>>>(countsV, offV, curV, NVV);
  csr_scatter<<<(NEE + T - 1) / T, T, 0, stream>>>(eic, eiv, curC, ceA, csA, NEE);
  csr_scatter<<<(NEE + T - 1) / T, T, 0, stream>>>(eiv, eic, curV, ceB, csB, NEE);

  // ================= Stage A: con update (src=var, dst=con) =================
  gemm(con_comb_bf, WT[0], cu_bq, bufC1, nullptr, 0, 0, nullptr, nullptr, nullptr, nullptr, NCC, 0, stream); // q_c
  gemm(con_comb_bf, WT[4], cu_bs, bufC2, nullptr, 0, 0, nullptr, nullptr, nullptr, nullptr, NCC, 0, stream); // skip_c
  gemm(var_comb_bf, WT[1], cu_bk, bufV1, nullptr, 0, 0, nullptr, nullptr, nullptr, nullptr, NVV, 0, stream); // k_v
  gemm(var_comb_bf, WT[2], cu_bv, bufV2, nullptr, 0, 0, nullptr, nullptr, nullptr, nullptr, NVV, 0, stream); // v_v
  gemm(edge_comb_bf, WT[3], nullptr, nullptr, ee_bf, 128, 0, nullptr, nullptr, nullptr, nullptr, NEE, 0, stream); // ee
  fused_attn<<<(NCC + 3) / 4, 256, 0, stream>>>(bufC1, bufV1, bufV2, ee_bf, offC, ceA, csA,
                                                bufC2, out_con, con_comb_bf, NCC);

  // ================= Stage B: var update (src=new con, dst=var) =================
  gemm(var_comb_bf, WT[5], vu_bq, bufV1, nullptr, 0, 0, nullptr, nullptr, nullptr, nullptr, NVV, 0, stream); // q_v
  gemm(var_comb_bf, WT[9], vu_bs, bufV2, nullptr, 0, 0, nullptr, nullptr, nullptr, nullptr, NVV, 0, stream); // skip_v
  gemm(con_comb_bf, WT[6], vu_bk, bufC1, nullptr, 0, 0, nullptr, nullptr, nullptr, nullptr, NCC, 0, stream); // k_c
  gemm(con_comb_bf, WT[7], vu_bv, bufC2, nullptr, 0, 0, nullptr, nullptr, nullptr, nullptr, NCC, 0, stream); // v_c
  gemm(edge_comb_bf, WT[8], nullptr, nullptr, ee_bf, 128, 0, nullptr, nullptr, nullptr, nullptr, NEE, 0, stream); // ee2
  fused_attn<<<(NVV + 3) / 4, 256, 0, stream>>>(bufV1, bufC1, bufC2, ee_bf, offV, ceB, csB,
                                                bufV2, out_var, var_comb_bf, NVV);

  // ================= Edge stage =================
  gemm(var_comb_bf, WT[10], eu_vb1, nullptr, hidV_bf, KP, 1, nullptr, nullptr, nullptr, nullptr, NVV, 1, stream);
  gemm(hidV_bf, WT[11], eu_vb2, nullptr, vc_bf, KP, 1, nullptr, nullptr, nullptr, nullptr, NVV, 1, stream);      // vc
  gemm(vc_bf, WT[15], nullptr, bufV1, nullptr, 0, 0, nullptr, nullptr, nullptr, nullptr, NVV, 0, stream);        // vcW
  gemm(con_comb_bf, WT[12], eu_cb1, nullptr, hidC_bf, KP, 1, nullptr, nullptr, nullptr, nullptr, NCC, 1, stream);
  gemm(hidC_bf, WT[13], eu_cb2, nullptr, cc_bf, KP, 1, nullptr, nullptr, nullptr, nullptr, NCC, 1, stream);      // cc
  gemm(cc_bf, WT[16], nullptr, bufC1, nullptr, 0, 0, nullptr, nullptr, nullptr, nullptr, NCC, 0, stream);        // ccW
  // t_e fused: edge_comb @ eW1[0:136] + vcW[eiv] + ccW[eic] + b1, relu -> bf16 [NE,160]
  gemm(edge_comb_bf, WT[14], eu_eb1, nullptr, te_bf, KP, 1, bufV1, bufC1, eiv, eic, NEE, 1, stream);
  gemm(te_bf, WT[17], eu_eb2, out_edge, nullptr, 0, 0, nullptr, nullptr, nullptr, nullptr, NEE, 1, stream);      // edge_new
}